// Round 2
// baseline (211.187 us; speedup 1.0000x reference)
//
#include <hip/hip_runtime.h>

// Problem constants
#define B_ 64
#define T_ 512
#define D_ 1024
#define S_ 1024
#define U_ 10

// workspace layout (in floats)
static constexpr int WS_C   = 0;        // [64][10]
static constexpr int WS_PMZ = 640;      // [512][2]
static constexpr int WS_E   = 1664;     // [64][512]
static constexpr int WS_PV  = 34432;    // [512][1024]

// ---------------------------------------------------------------------------
// DPP wave64 sum: row_shr 1/2/4/8 + row_bcast15 + row_bcast31, zero-filled.
// Result lands in lane 63; readlane(63) broadcasts as a uniform value.
// No DS ops — pure VALU.
// ---------------------------------------------------------------------------
template <int CTRL>
__device__ __forceinline__ float dpp_add(float x) {
    int yi = __builtin_amdgcn_update_dpp(0, __float_as_int(x), CTRL, 0xf, 0xf, true);
    return x + __int_as_float(yi);
}

__device__ __forceinline__ float wave_sum_uniform(float x) {
    x = dpp_add<0x111>(x);   // row_shr:1
    x = dpp_add<0x112>(x);   // row_shr:2
    x = dpp_add<0x114>(x);   // row_shr:4
    x = dpp_add<0x118>(x);   // row_shr:8  -> lane 15 of each row has row sum
    x = dpp_add<0x142>(x);   // row_bcast15 -> lane 31 = r0+r1, lane 63 = r2+r3
    x = dpp_add<0x143>(x);   // row_bcast31 -> lane 63 = total
    return __int_as_float(__builtin_amdgcn_readlane(__float_as_int(x), 63));
}

// ---------------------------------------------------------------------------
// K0: c[b][u] = sum_s s_prev[b][s] * W1[D+s][u] + b1[u]
// ---------------------------------------------------------------------------
__global__ __launch_bounds__(256) void k0_cprev(const float* __restrict__ s_prev,
                                                const float* __restrict__ W1,
                                                const float* __restrict__ b1,
                                                float* __restrict__ ws) {
    const int b = blockIdx.x;
    const int tid = threadIdx.x;

    const float4 s4 = *(const float4*)(s_prev + b * S_ + tid * 4);
    float sv[4] = {s4.x, s4.y, s4.z, s4.w};

    float acc[U_];
#pragma unroll
    for (int u = 0; u < U_; u++) acc[u] = 0.f;

    const float* wp = W1 + (size_t)(D_ + tid * 4) * U_;
#pragma unroll
    for (int q = 0; q < 10; q++) {
        float4 t = ((const float4*)wp)[q];
        float tv[4] = {t.x, t.y, t.z, t.w};
#pragma unroll
        for (int i = 0; i < 4; i++) {
            int f = q * 4 + i;
            int j = f / U_;
            int u = f % U_;
            acc[u] += sv[j] * tv[i];
        }
    }

    __shared__ float red[256][U_];
#pragma unroll
    for (int u = 0; u < U_; u++) red[tid][u] = acc[u];
    __syncthreads();
    for (int off = 128; off > 0; off >>= 1) {
        if (tid < off) {
#pragma unroll
            for (int u = 0; u < U_; u++) red[tid][u] += red[tid + off][u];
        }
        __syncthreads();
    }
    if (tid < U_) ws[WS_C + b * U_ + tid] = red[0][tid] + b1[tid];
}

// ---------------------------------------------------------------------------
// K1: main pass. 512 blocks = 64 batches x 8 t-chunks of 64.
// 4 waves/block, each wave owns 16 consecutive t; lane owns 16 d's.
// Per-t reduction via DPP (no DS); e is wave-uniform after readlane.
// ---------------------------------------------------------------------------
__global__ __launch_bounds__(256, 2) void k1_main(const float* __restrict__ a,
                                                  const float* __restrict__ W1,
                                                  const float* __restrict__ W2,
                                                  const float* __restrict__ b2,
                                                  float* __restrict__ ws) {
    const int blk  = blockIdx.x;
    const int b    = blk >> 3;
    const int p    = blk & 7;
    const int tid  = threadIdx.x;
    const int wave = tid >> 6;
    const int lane = tid & 63;

    // W1[:D] fragment for this lane's d-set (160 VGPRs)
    float w1f[4][40];
#pragma unroll
    for (int k = 0; k < 4; k++) {
        const float* wp = W1 + (size_t)(k * 256 + lane * 4) * U_;
#pragma unroll
        for (int q = 0; q < 10; q++) {
            float4 t = ((const float4*)wp)[q];
            w1f[k][q * 4 + 0] = t.x;
            w1f[k][q * 4 + 1] = t.y;
            w1f[k][q * 4 + 2] = t.z;
            w1f[k][q * 4 + 3] = t.w;
        }
    }

    // wave-uniform small params -> force into scalar domain
    float c[U_], w2v[U_];
#pragma unroll
    for (int u = 0; u < U_; u++)
        c[u] = __int_as_float(__builtin_amdgcn_readfirstlane(
                   __float_as_int(ws[WS_C + b * U_ + u])));
#pragma unroll
    for (int u = 0; u < U_; u++)
        w2v[u] = __int_as_float(__builtin_amdgcn_readfirstlane(__float_as_int(W2[u])));
    const float b2s = __int_as_float(__builtin_amdgcn_readfirstlane(__float_as_int(b2[0])));

    float v[4][4];
#pragma unroll
    for (int k = 0; k < 4; k++)
#pragma unroll
        for (int j = 0; j < 4; j++) v[k][j] = 0.f;
    float m = -1e30f, Z = 0.f;

    const int t0 = p * 64 + wave * 16;
    const float* abase = a + ((size_t)(b * T_ + t0)) * D_ + lane * 4;

    for (int tt = 0; tt < 16; tt++) {
        const float* ap = abase + (size_t)tt * D_;
        float av[4][4];
#pragma unroll
        for (int k = 0; k < 4; k++) {
            float4 t = *(const float4*)(ap + k * 256);
            av[k][0] = t.x; av[k][1] = t.y; av[k][2] = t.z; av[k][3] = t.w;
        }

        float acc[U_];
#pragma unroll
        for (int u = 0; u < U_; u++) acc[u] = 0.f;
#pragma unroll
        for (int k = 0; k < 4; k++)
#pragma unroll
            for (int j = 0; j < 4; j++)
#pragma unroll
                for (int u = 0; u < U_; u++)
                    acc[u] += av[k][j] * w1f[k][j * 10 + u];

        // e = relu(sum_u tanh(acc+c) * w2 + b2), computed uniformly
        float e = b2s;
#pragma unroll
        for (int u = 0; u < U_; u++) {
            float s = wave_sum_uniform(acc[u]);     // 6 DPP adds + readlane, no DS
            float x = s + c[u];
            x = fminf(fmaxf(x, -15.f), 15.f);
            float ex = __expf(2.f * x);
            float th = 1.f - 2.f * __builtin_amdgcn_rcpf(ex + 1.f);
            e += th * w2v[u];
        }
        e = fmaxf(e, 0.f);
        if (lane == 0) ws[WS_E + b * T_ + t0 + tt] = e;

        // online softmax update
        float mn = fmaxf(m, e);
        float sc = __expf(m - mn);
        float w  = __expf(e - mn);
        Z = Z * sc + w;
#pragma unroll
        for (int k = 0; k < 4; k++)
#pragma unroll
            for (int j = 0; j < 4; j++) v[k][j] = v[k][j] * sc + w * av[k][j];
        m = mn;
    }

    // block combine across 4 waves
    __shared__ float4 vs4[4][256];
    __shared__ float  mzs[4][2];
#pragma unroll
    for (int k = 0; k < 4; k++)
        vs4[wave][k * 64 + lane] = make_float4(v[k][0], v[k][1], v[k][2], v[k][3]);
    if (lane == 0) { mzs[wave][0] = m; mzs[wave][1] = Z; }
    __syncthreads();

    float m0 = mzs[0][0], m1 = mzs[1][0], m2 = mzs[2][0], m3 = mzs[3][0];
    float mb = fmaxf(fmaxf(m0, m1), fmaxf(m2, m3));
    float f0 = __expf(m0 - mb), f1 = __expf(m1 - mb);
    float f2 = __expf(m2 - mb), f3 = __expf(m3 - mb);
    float Zb = f0 * mzs[0][1] + f1 * mzs[1][1] + f2 * mzs[2][1] + f3 * mzs[3][1];

    float4 t0v = vs4[0][tid], t1v = vs4[1][tid], t2v = vs4[2][tid], t3v = vs4[3][tid];
    float4 o;
    o.x = f0 * t0v.x + f1 * t1v.x + f2 * t2v.x + f3 * t3v.x;
    o.y = f0 * t0v.y + f1 * t1v.y + f2 * t2v.y + f3 * t3v.y;
    o.z = f0 * t0v.z + f1 * t1v.z + f2 * t2v.z + f3 * t3v.z;
    o.w = f0 * t0v.w + f1 * t1v.w + f2 * t2v.w + f3 * t3v.w;
    ((float4*)(ws + WS_PV))[blk * 256 + tid] = o;
    if (tid == 0) { ws[WS_PMZ + blk * 2] = mb; ws[WS_PMZ + blk * 2 + 1] = Zb; }
}

// ---------------------------------------------------------------------------
// K2: final combine per batch (8 partials) -> context + scores
// ---------------------------------------------------------------------------
__global__ __launch_bounds__(256) void k2_final(const float* __restrict__ ws,
                                                float* __restrict__ out) {
    const int b = blockIdx.x;
    const int tid = threadIdx.x;

    float pm[8], pz[8];
    float mb = -1e30f;
#pragma unroll
    for (int p = 0; p < 8; p++) {
        pm[p] = ws[WS_PMZ + (b * 8 + p) * 2];
        pz[p] = ws[WS_PMZ + (b * 8 + p) * 2 + 1];
        mb = fmaxf(mb, pm[p]);
    }
    float f[8], Z = 0.f;
#pragma unroll
    for (int p = 0; p < 8; p++) { f[p] = __expf(pm[p] - mb); Z += f[p] * pz[p]; }
    const float rz = 1.f / Z;

    float4 o = make_float4(0.f, 0.f, 0.f, 0.f);
#pragma unroll
    for (int p = 0; p < 8; p++) {
        float4 t = ((const float4*)(ws + WS_PV))[(b * 8 + p) * 256 + tid];
        o.x += f[p] * t.x; o.y += f[p] * t.y; o.z += f[p] * t.z; o.w += f[p] * t.w;
    }
    o.x *= rz; o.y *= rz; o.z *= rz; o.w *= rz;
    ((float4*)out)[b * 256 + tid] = o;

    for (int t = tid; t < T_; t += 256) {
        out[B_ * D_ + b * T_ + t] = __expf(ws[WS_E + b * T_ + t] - mb) * rz;
    }
}

// ---------------------------------------------------------------------------
extern "C" void kernel_launch(void* const* d_in, const int* in_sizes, int n_in,
                              void* d_out, int out_size, void* d_ws, size_t ws_size,
                              hipStream_t stream) {
    const float* a      = (const float*)d_in[0];
    const float* s_prev = (const float*)d_in[1];
    const float* W1     = (const float*)d_in[2];
    const float* b1     = (const float*)d_in[3];
    const float* W2     = (const float*)d_in[4];
    const float* b2     = (const float*)d_in[5];
    float* out = (float*)d_out;
    float* ws  = (float*)d_ws;

    k0_cprev<<<dim3(B_), dim3(256), 0, stream>>>(s_prev, W1, b1, ws);
    k1_main<<<dim3(B_ * 8), dim3(256), 0, stream>>>(a, W1, W2, b2, ws);
    k2_final<<<dim3(B_), dim3(256), 0, stream>>>(ws, out);
}

// Round 3
// 209.570 us; speedup vs baseline: 1.0077x; 1.0077x over previous
//
#include <hip/hip_runtime.h>

// Problem constants
#define B_ 64
#define T_ 512
#define D_ 1024
#define S_ 1024
#define U_ 10

// workspace layout (in floats)
static constexpr int WS_PMZ = 0;        // [512][2]  per-block partial (m, Z)
static constexpr int WS_E   = 1024;     // [64][512] raw e values
static constexpr int WS_PV  = 33792;    // [512][1024] per-block partial weighted sums

// ---------------------------------------------------------------------------
// DPP wave64 sum -> uniform (SGPR) value. No DS ops.
// ---------------------------------------------------------------------------
template <int CTRL>
__device__ __forceinline__ float dpp_add(float x) {
    int yi = __builtin_amdgcn_update_dpp(0, __float_as_int(x), CTRL, 0xf, 0xf, true);
    return x + __int_as_float(yi);
}

__device__ __forceinline__ float wave_sum_uniform(float x) {
    x = dpp_add<0x111>(x);   // row_shr:1
    x = dpp_add<0x112>(x);   // row_shr:2
    x = dpp_add<0x114>(x);   // row_shr:4
    x = dpp_add<0x118>(x);   // row_shr:8
    x = dpp_add<0x142>(x);   // row_bcast15
    x = dpp_add<0x143>(x);   // row_bcast31 -> lane 63 = total
    return __int_as_float(__builtin_amdgcn_readlane(__float_as_int(x), 63));
}

__device__ __forceinline__ float uload(const float* p) {
    return __int_as_float(__builtin_amdgcn_readfirstlane(__float_as_int(*p)));
}

// ---------------------------------------------------------------------------
// K1: fused main pass. 512 blocks = 64 batches x 8 t-chunks of 64.
// 4 waves/block, each wave owns 16 consecutive t; lane owns 16 d's.
// Phase A: wave redundantly computes c[u] = s_prev[b]·W1[D:,u] + b1[u].
// Phase B: online softmax over t with register-double-buffered a loads.
// ---------------------------------------------------------------------------
__global__ __launch_bounds__(256, 2) void k1_main(const float* __restrict__ a,
                                                  const float* __restrict__ s_prev,
                                                  const float* __restrict__ W1,
                                                  const float* __restrict__ b1,
                                                  const float* __restrict__ W2,
                                                  const float* __restrict__ b2,
                                                  float* __restrict__ ws) {
    const int blk  = blockIdx.x;
    const int b    = blk >> 3;
    const int p    = blk & 7;
    const int tid  = threadIdx.x;
    const int wave = tid >> 6;
    const int lane = tid & 63;

    // ---- Phase A: per-wave c[u] (done BEFORE w1f to keep VGPR peak low) ----
    float c[U_];
    {
        float cacc[U_];
#pragma unroll
        for (int u = 0; u < U_; u++) cacc[u] = 0.f;
#pragma unroll
        for (int r = 0; r < 4; r++) {
            const float4 s4 = *(const float4*)(s_prev + b * S_ + r * 256 + lane * 4);
            const float svv[4] = {s4.x, s4.y, s4.z, s4.w};
#pragma unroll
            for (int i = 0; i < 4; i++) {
                const int s = r * 256 + lane * 4 + i;
                const float* wp = W1 + (size_t)(D_ + s) * U_;   // 8B-aligned
#pragma unroll
                for (int h = 0; h < 5; h++) {
                    float2 t = ((const float2*)wp)[h];
                    cacc[2 * h]     += svv[i] * t.x;
                    cacc[2 * h + 1] += svv[i] * t.y;
                }
            }
        }
#pragma unroll
        for (int u = 0; u < U_; u++)
            c[u] = wave_sum_uniform(cacc[u]) + uload(b1 + u);
    }

    float w2v[U_];
#pragma unroll
    for (int u = 0; u < U_; u++) w2v[u] = uload(W2 + u);
    const float b2s = uload(b2);

    // ---- W1[:D] fragment for this lane's d-set (160 VGPRs) ----
    float w1f[4][40];
#pragma unroll
    for (int k = 0; k < 4; k++) {
        const float* wp = W1 + (size_t)(k * 256 + lane * 4) * U_;
#pragma unroll
        for (int q = 0; q < 10; q++) {
            float4 t = ((const float4*)wp)[q];
            w1f[k][q * 4 + 0] = t.x;
            w1f[k][q * 4 + 1] = t.y;
            w1f[k][q * 4 + 2] = t.z;
            w1f[k][q * 4 + 3] = t.w;
        }
    }

    // ---- Phase B: online softmax over 16 t with double-buffered loads ----
    float v[4][4];
#pragma unroll
    for (int k = 0; k < 4; k++)
#pragma unroll
        for (int j = 0; j < 4; j++) v[k][j] = 0.f;
    float m = -1e30f, Z = 0.f;

    const int t0 = p * 64 + wave * 16;
    const float* abase = a + ((size_t)(b * T_ + t0)) * D_ + lane * 4;

    float4 cur[4], nxt[4];
#pragma unroll
    for (int k = 0; k < 4; k++) cur[k] = *(const float4*)(abase + k * 256);

#pragma unroll 2
    for (int tt = 0; tt < 16; tt++) {
        // issue next-t loads FIRST so they overlap this iteration's compute
        if (tt < 15) {
            const float* apn = abase + (size_t)(tt + 1) * D_;
#pragma unroll
            for (int k = 0; k < 4; k++) nxt[k] = *(const float4*)(apn + k * 256);
        }

        float av[4][4];
#pragma unroll
        for (int k = 0; k < 4; k++) {
            av[k][0] = cur[k].x; av[k][1] = cur[k].y;
            av[k][2] = cur[k].z; av[k][3] = cur[k].w;
        }

        float acc[U_];
#pragma unroll
        for (int u = 0; u < U_; u++) acc[u] = 0.f;
#pragma unroll
        for (int k = 0; k < 4; k++)
#pragma unroll
            for (int j = 0; j < 4; j++)
#pragma unroll
                for (int u = 0; u < U_; u++)
                    acc[u] += av[k][j] * w1f[k][j * 10 + u];

        // e = relu(sum_u tanh(acc+c) * w2 + b2), wave-uniform
        float e = b2s;
#pragma unroll
        for (int u = 0; u < U_; u++) {
            float s = wave_sum_uniform(acc[u]);
            float x = s + c[u];
            x = fminf(fmaxf(x, -15.f), 15.f);
            float ex = __expf(2.f * x);
            float th = 1.f - 2.f * __builtin_amdgcn_rcpf(ex + 1.f);
            e += th * w2v[u];
        }
        e = fmaxf(e, 0.f);
        if (lane == 0) ws[WS_E + b * T_ + t0 + tt] = e;

        // online softmax update
        float mn = fmaxf(m, e);
        float sc = __expf(m - mn);
        float w  = __expf(e - mn);
        Z = Z * sc + w;
#pragma unroll
        for (int k = 0; k < 4; k++)
#pragma unroll
            for (int j = 0; j < 4; j++) v[k][j] = v[k][j] * sc + w * av[k][j];
        m = mn;

#pragma unroll
        for (int k = 0; k < 4; k++) cur[k] = nxt[k];
    }

    // ---- block combine across 4 waves ----
    __shared__ float4 vs4[4][256];
    __shared__ float  mzs[4][2];
#pragma unroll
    for (int k = 0; k < 4; k++)
        vs4[wave][k * 64 + lane] = make_float4(v[k][0], v[k][1], v[k][2], v[k][3]);
    if (lane == 0) { mzs[wave][0] = m; mzs[wave][1] = Z; }
    __syncthreads();

    float m0 = mzs[0][0], m1 = mzs[1][0], m2 = mzs[2][0], m3 = mzs[3][0];
    float mb = fmaxf(fmaxf(m0, m1), fmaxf(m2, m3));
    float f0 = __expf(m0 - mb), f1 = __expf(m1 - mb);
    float f2 = __expf(m2 - mb), f3 = __expf(m3 - mb);
    float Zb = f0 * mzs[0][1] + f1 * mzs[1][1] + f2 * mzs[2][1] + f3 * mzs[3][1];

    float4 t0v = vs4[0][tid], t1v = vs4[1][tid], t2v = vs4[2][tid], t3v = vs4[3][tid];
    float4 o;
    o.x = f0 * t0v.x + f1 * t1v.x + f2 * t2v.x + f3 * t3v.x;
    o.y = f0 * t0v.y + f1 * t1v.y + f2 * t2v.y + f3 * t3v.y;
    o.z = f0 * t0v.z + f1 * t1v.z + f2 * t2v.z + f3 * t3v.z;
    o.w = f0 * t0v.w + f1 * t1v.w + f2 * t2v.w + f3 * t3v.w;
    ((float4*)(ws + WS_PV))[blk * 256 + tid] = o;
    if (tid == 0) { ws[WS_PMZ + blk * 2] = mb; ws[WS_PMZ + blk * 2 + 1] = Zb; }
}

// ---------------------------------------------------------------------------
// K2: final combine per batch (8 partials) -> context + scores
// ---------------------------------------------------------------------------
__global__ __launch_bounds__(256) void k2_final(const float* __restrict__ ws,
                                                float* __restrict__ out) {
    const int b = blockIdx.x;
    const int tid = threadIdx.x;

    float pm[8], pz[8];
    float mb = -1e30f;
#pragma unroll
    for (int p = 0; p < 8; p++) {
        pm[p] = ws[WS_PMZ + (b * 8 + p) * 2];
        pz[p] = ws[WS_PMZ + (b * 8 + p) * 2 + 1];
        mb = fmaxf(mb, pm[p]);
    }
    float f[8], Z = 0.f;
#pragma unroll
    for (int p = 0; p < 8; p++) { f[p] = __expf(pm[p] - mb); Z += f[p] * pz[p]; }
    const float rz = 1.f / Z;

    float4 o = make_float4(0.f, 0.f, 0.f, 0.f);
#pragma unroll
    for (int p = 0; p < 8; p++) {
        float4 t = ((const float4*)(ws + WS_PV))[(b * 8 + p) * 256 + tid];
        o.x += f[p] * t.x; o.y += f[p] * t.y; o.z += f[p] * t.z; o.w += f[p] * t.w;
    }
    o.x *= rz; o.y *= rz; o.z *= rz; o.w *= rz;
    ((float4*)out)[b * 256 + tid] = o;

    for (int t = tid; t < T_; t += 256) {
        out[B_ * D_ + b * T_ + t] = __expf(ws[WS_E + b * T_ + t] - mb) * rz;
    }
}

// ---------------------------------------------------------------------------
extern "C" void kernel_launch(void* const* d_in, const int* in_sizes, int n_in,
                              void* d_out, int out_size, void* d_ws, size_t ws_size,
                              hipStream_t stream) {
    const float* a      = (const float*)d_in[0];
    const float* s_prev = (const float*)d_in[1];
    const float* W1     = (const float*)d_in[2];
    const float* b1     = (const float*)d_in[3];
    const float* W2     = (const float*)d_in[4];
    const float* b2     = (const float*)d_in[5];
    float* out = (float*)d_out;
    float* ws  = (float*)d_ws;

    k1_main<<<dim3(B_ * 8), dim3(256), 0, stream>>>(a, s_prev, W1, b1, W2, b2, ws);
    k2_final<<<dim3(B_), dim3(256), 0, stream>>>(ws, out);
}